// Round 4
// baseline (851.019 us; speedup 1.0000x reference)
//
#include <hip/hip_runtime.h>

#define TT    32        // timesteps
#define KDIM  262144    // fan-in (C*RF*L)
#define NFEAT 512       // output features
#define NFB   16        // features per block
#define FPT   8         // features per thread
#define TPT   8         // timesteps per thread
#define BK    256       // k elements staged per step
#define NBUF  3         // LDS ring depth

// async global->LDS, 16B per lane; LDS dest = wave-uniform row base + lane*16
__device__ __forceinline__ void async_ld16(const float* g, float* lds_row) {
    __builtin_amdgcn_global_load_lds(
        (const __attribute__((address_space(1))) unsigned int*)g,
        (__attribute__((address_space(3))) unsigned int*)lds_row, 16, 0, 0);
}

// ---------------------------------------------------------------------------
// Kernel 1: partial GEMM. grid = (32 f-tiles, nkc k-chunks), block = 512.
// 8 waves = 2 fgrps x 4 tgrps; per-thread register tile 8 features x 8 t
// (16 ds_read_b128 per 256 FMAs -- 1.5x less LDS traffic than 4x8).
// Ring-3 LDS pipeline (144 KB, 1 block/CU): per step each wave issues 6
// global_load_lds (4 x-rows + 2 w-rows), then waits s_waitcnt vmcnt(6)
// (retires all but the newest stage -> 2 compute phases of latency cover,
// never drains to 0 in the loop) + raw s_barrier. Stage of step i+2
// (overwriting slot (i-1)%3) is issued only after barrier i, which all
// waves reach only after finishing compute i-1 -> race-free.
// Numerics: per-(f,t,kchunk) k-order, butterfly and partial layout are
// identical to the verified kernel -> bit-exact output.
// (Resubmission: round-3 bench aborted on container failure, no GPU signal.)
// ---------------------------------------------------------------------------
__global__ __launch_bounds__(512, 2)
void gemm_partial(const float* __restrict__ x, const float* __restrict__ w,
                  float* __restrict__ partial, int KC) {
    __shared__ float xs[NBUF][TT][BK];    // 3 x 32 KB = 96 KB
    __shared__ float ws[NBUF][NFB][BK];   // 3 x 16 KB = 48 KB

    const int tid  = threadIdx.x;
    const int lane = tid & 63;
    const int wave = tid >> 6;           // 0..7
    const int fgrp = wave & 1;           // 0..1
    const int tgrp = wave >> 1;          // 0..3
    const int ftile  = blockIdx.x;       // 0..31
    const int kchunk = blockIdx.y;       // 0..nkc-1
    const int fbase = ftile * NFB;
    const int f0 = fbase + fgrp * FPT;
    const int t0 = tgrp * TPT;
    const int xrow = wave * 4;           // 4 x-rows per wave
    const int wrow = wave * 2;           // 2 w-rows per wave
    const size_t kbase = (size_t)kchunk * (size_t)KC;

    float acc[FPT][TPT];
#pragma unroll
    for (int j = 0; j < FPT; ++j)
#pragma unroll
        for (int t = 0; t < TPT; ++t) acc[j][t] = 0.f;

    const float* xsrc = x + kbase + (lane << 2);
    const float* wsrc = w + kbase + (lane << 2);

    auto stage = [&](int b, int step) {
        const size_t ko = (size_t)step * BK;
#pragma unroll
        for (int r = 0; r < 4; ++r)
            async_ld16(xsrc + (size_t)(xrow + r) * KDIM + ko, &xs[b][xrow + r][0]);
#pragma unroll
        for (int r = 0; r < 2; ++r)
            async_ld16(wsrc + (size_t)(fbase + wrow + r) * KDIM + ko, &ws[b][wrow + r][0]);
    };

    auto compute = [&](int b) {
        const float* xb = &xs[b][0][0];
        const float* wb = &ws[b][0][0];
        float4 wv[FPT];
#pragma unroll
        for (int j = 0; j < FPT; ++j)
            wv[j] = *(const float4*)(wb + (fgrp * FPT + j) * BK + (lane << 2));
#pragma unroll
        for (int t = 0; t < TPT; ++t) {
            const float4 xv = *(const float4*)(xb + (t0 + t) * BK + (lane << 2));
#pragma unroll
            for (int j = 0; j < FPT; ++j) {
                acc[j][t] = fmaf(wv[j].x, xv.x, acc[j][t]);
                acc[j][t] = fmaf(wv[j].y, xv.y, acc[j][t]);
                acc[j][t] = fmaf(wv[j].z, xv.z, acc[j][t]);
                acc[j][t] = fmaf(wv[j].w, xv.w, acc[j][t]);
            }
        }
    };

    const int nsteps = KC / BK;          // >= 32, KC is a multiple of BK

    // prologue: two stages in flight (12 outstanding loads per wave)
    stage(0, 0);
    stage(1, 1);

    int buf = 0;
    for (int i = 0; i < nsteps - 1; ++i) {
        // retire everything except the newest stage -> stage i is in LDS
        asm volatile("s_waitcnt vmcnt(6)" ::: "memory");
        __builtin_amdgcn_s_barrier();    // all waves' stage i landed; all done with step i-1
        if (i + 2 < nsteps) {
            int b2 = buf + 2; if (b2 >= NBUF) b2 -= NBUF;
            stage(b2, i + 2);            // overwrites slot (i-1)%3 -- safe after barrier
        }
        compute(buf);
        if (++buf == NBUF) buf = 0;
    }
    // peeled last step: nothing left in flight except its own stage
    asm volatile("s_waitcnt vmcnt(0)" ::: "memory");
    __builtin_amdgcn_s_barrier();
    compute(buf);

    // butterfly reduce across the 64 k-lanes
#pragma unroll
    for (int j = 0; j < FPT; ++j) {
#pragma unroll
        for (int t = 0; t < TPT; ++t) {
            float v = acc[j][t];
            v += __shfl_xor(v, 32, 64);
            v += __shfl_xor(v, 16, 64);
            v += __shfl_xor(v,  8, 64);
            v += __shfl_xor(v,  4, 64);
            v += __shfl_xor(v,  2, 64);
            v += __shfl_xor(v,  1, 64);
            acc[j][t] = v;
        }
    }

    if (lane == 0) {
#pragma unroll
        for (int j = 0; j < FPT; ++j) {
            float* p = partial + ((size_t)kchunk * NFEAT + (f0 + j)) * TT + t0;
            *(float4*)(p)     = make_float4(acc[j][0], acc[j][1], acc[j][2], acc[j][3]);
            *(float4*)(p + 4) = make_float4(acc[j][4], acc[j][5], acc[j][6], acc[j][7]);
        }
    }
}

// ---------------------------------------------------------------------------
// Kernel 2a: deterministic reduction over k-chunks -> raw potentials [o][t]
// ---------------------------------------------------------------------------
__global__ __launch_bounds__(256)
void reduce_chunks(const float* __restrict__ partial, int nkc,
                   float* __restrict__ potraw) {
    const int id = blockIdx.x * 256 + threadIdx.x;   // 0..16383 = o*32+t
    float s = 0.f;
    for (int c = 0; c < nkc; ++c)
        s += partial[(size_t)c * (NFEAT * TT) + id];
    potraw[id] = s;
}

// ---------------------------------------------------------------------------
// Kernel 2b: threshold + spike logic + 8-winner k-WTA + binary output.
// Single block, 512 threads. Reductions run on wave 0 via shuffles
// (4 barriers total instead of ~81). Exact fp32 replication of the
// reference epilogue, numpy-argmax first-index tie-break included.
// ---------------------------------------------------------------------------
__global__ __launch_bounds__(512)
void finalize(const float* __restrict__ potraw, float* __restrict__ out) {
    const int o = threadIdx.x;       // feature index

    float pot[TT];
#pragma unroll
    for (int t = 0; t < TT; ++t) {
        const float s = potraw[o * TT + t];
        pot[t] = (s < 0.2f) ? 0.f : s;     // zero strictly below threshold
    }

    int cnt = 0;
#pragma unroll
    for (int t = 0; t < TT; ++t) cnt += (pot[t] > 0.f) ? 1 : 0;

    int first = TT - cnt;                  // clip((T - count), 0, T-1)
    if (first > TT - 1) first = TT - 1;
    float value = 0.f;
#pragma unroll
    for (int t = 0; t < TT; ++t)
        if (t == first) value = pot[t];

    __shared__ float rv[NFEAT];
    __shared__ float tot[NFEAT];
    __shared__ int   sel[NFEAT];
    __shared__ float vbc;

    rv[o]  = (cnt > 0) ? value : 0.f;      // spikes*values, max over t
    sel[o] = 0;
    __syncthreads();

    // ---- v = max(spikes * values) * T   (wave 0, shuffle reduce)
    if (o < 64) {
        float m = rv[o];
#pragma unroll
        for (int j = 1; j < 8; ++j) m = fmaxf(m, rv[o + 64 * j]);
#pragma unroll
        for (int s = 32; s; s >>= 1) m = fmaxf(m, __shfl_xor(m, s, 64));
        if (o == 0) vbc = m * (float)TT;
    }
    __syncthreads();
    const float v = vbc;

    // total[o] = count * value + count * v   (0 when no spikes)
    tot[o] = (float)cnt * (value + v);
    __syncthreads();

    // ---- iterative k-WTA, 8 winners, first-index argmax ties (wave 0)
    if (o < 64) {
        float tv[8];                       // tv[j] holds tot[o + 64*j]
#pragma unroll
        for (int j = 0; j < 8; ++j) tv[j] = tot[o + 64 * j];
        for (int it = 0; it < 8; ++it) {
            float bv = tv[0]; int bi = o;
#pragma unroll
            for (int j = 1; j < 8; ++j) {
                const int idx = o + 64 * j;
                if (tv[j] > bv || (tv[j] == bv && idx < bi)) { bv = tv[j]; bi = idx; }
            }
#pragma unroll
            for (int s = 32; s; s >>= 1) {
                const float ov = __shfl_xor(bv, s, 64);
                const int   oi = __shfl_xor(bi, s, 64);
                if (ov > bv || (ov == bv && oi < bi)) { bv = ov; bi = oi; }
            }
            // all lanes agree on (bv, bi): select if nonzero, always inhibit
            if (bv != 0.f && o == (bi & 63)) sel[bi] = 1;
#pragma unroll
            for (int j = 0; j < 8; ++j)
                if (o + 64 * j == bi) tv[j] = 0.f;   // static index (unrolled)
        }
    }
    __syncthreads();

    // ---- out[t, o] = binary spikes of selected features
#pragma unroll
    for (int t = 0; t < TT; ++t)
        out[t * NFEAT + o] = (sel[o] && pot[t] > 0.f) ? 1.f : 0.f;
}

// ---------------------------------------------------------------------------
extern "C" void kernel_launch(void* const* d_in, const int* in_sizes, int n_in,
                              void* d_out, int out_size, void* d_ws, size_t ws_size,
                              hipStream_t stream) {
    const float* x = (const float*)d_in[0];   // rec_field (32,1,64,4096)
    const float* w = (const float*)d_in[1];   // weight   (512,1,64,4096)
    float* out = (float*)d_out;               // (32,512,1,1) flat

    // partials [nkc][512][32] + potraw [512][32] in workspace
    int nkc = 32;
    while (nkc > 1 &&
           ((size_t)(nkc + 1) * NFEAT * TT * sizeof(float)) > ws_size)
        nkc >>= 1;
    const int KC = KDIM / nkc;

    float* partial = (float*)d_ws;
    float* potraw  = partial + (size_t)nkc * NFEAT * TT;

    gemm_partial<<<dim3(NFEAT / NFB, nkc), 512, 0, stream>>>(x, w, partial, KC);
    reduce_chunks<<<(NFEAT * TT) / 256, 256, 0, stream>>>(partial, nkc, potraw);
    finalize<<<1, NFEAT, 0, stream>>>(potraw, out);
}